// Round 4
// baseline (402.206 us; speedup 1.0000x reference)
//
#include <hip/hip_runtime.h>
#include <hip/hip_bf16.h>

typedef float v4f __attribute__((ext_vector_type(4)));
typedef short v8s __attribute__((ext_vector_type(8)));

__device__ __forceinline__ unsigned short f2bf(float x){
    unsigned u = __float_as_uint(x);
    u += 0x7FFFu + ((u >> 16) & 1u);
    return (unsigned short)(u >> 16);
}
__device__ __forceinline__ float bf2f(unsigned short h){
    return __uint_as_float(((unsigned)h) << 16);
}
__device__ __forceinline__ v8s pack_bf8(v4f a, v4f b){
    union { v8s s; __hip_bfloat162 h[4]; } u;
    u.h[0] = __float22bfloat162_rn(float2{a[0],a[1]});
    u.h[1] = __float22bfloat162_rn(float2{a[2],a[3]});
    u.h[2] = __float22bfloat162_rn(float2{b[0],b[1]});
    u.h[3] = __float22bfloat162_rn(float2{b[2],b[3]});
    return u.s;
}

// ---------------- merged prep kernel ----------------
__global__ __launch_bounds__(256) void prep_all(const float* __restrict__ targ,
        const float* __restrict__ kern, const float* __restrict__ ak,
        const float* __restrict__ semk, float* __restrict__ ns,
        unsigned short* __restrict__ packB, unsigned short* __restrict__ pack2){
    __shared__ float wsh[256*8];
    int blk = blockIdx.x, t = threadIdx.x;
    if (blk < 16){
        {   // W_node[d][h], d = t
            float a[8];
            #pragma unroll
            for (int h=0;h<8;h++) a[h]=0.f;
            const float* kr = kern + t*128;
            for (int c=0;c<128;c++){
                float kv = kr[c];
                #pragma unroll
                for (int h=0;h<8;h++) a[h] = fmaf(kv, ak[h*256+c], a[h]);
            }
            #pragma unroll
            for (int h=0;h<8;h++) wsh[t*8+h]=a[h];
        }
        __syncthreads();
        int b = blk*256 + t;
        float acc[8];
        #pragma unroll
        for (int h=0;h<8;h++) acc[h]=0.f;
        const float* tr = targ + (size_t)b*256;
        for (int d=0;d<256;d++){
            float tv = tr[d];
            #pragma unroll
            for (int h=0;h<8;h++) acc[h] = fmaf(tv, wsh[d*8+h], acc[h]);
        }
        #pragma unroll
        for (int h=0;h<8;h++) ns[b*8+h]=acc[h];
    } else if (blk < 18){
        {   // W_neigh[d][h], d = t
            float a[8];
            #pragma unroll
            for (int h=0;h<8;h++) a[h]=0.f;
            const float* kr = kern + t*128;
            for (int c=0;c<128;c++){
                float kv = kr[c];
                #pragma unroll
                for (int h=0;h<8;h++) a[h] = fmaf(kv, ak[h*256+128+c], a[h]);
            }
            #pragma unroll
            for (int h=0;h<8;h++) wsh[t*8+h]=a[h];
        }
        __syncthreads();
        int gt = (blk-16)*256 + t;            // 0..511
        for (int r=0;r<72;r++){
            int e = gt + r*512;                // < 36864
            int j = e & 7; int l = (e>>3) & 63;
            int fc = e >> 9; int cc = fc % 9; int kk = fc / 9;
            int d = kk*32 + (l>>4)*8 + j;
            int c = cc*16 + (l&15);
            float v;
            if (cc < 8) v = kern[d*128 + c];
            else { int h = c - 128; v = (h < 8) ? wsh[d*8+h] : 0.0f; }
            packB[e] = f2bf(v);
        }
    } else {
        int gt = (blk-18)*256 + t;            // 0..8191
        for (int r=0;r<16;r++){
            int e = gt + r*8192;               // < 131072
            int j = e & 7; int l = (e>>3) & 63;
            int cc = (e>>9) & 7; int gkk = e >> 12;   // 0..31
            int k = gkk*32 + (l>>4)*8 + j;
            int a2 = cc*16 + (l&15);
            pack2[e] = f2bf(semk[k*128 + a2]);
        }
    }
}

// ---------------- phase 1: persistent blocks, 2-deep reg tile-pipeline ----------------
// 512 blocks x 12 tiles. tile = (g, 2 b's) = 64 rows. Wave w owns m-tile rows w*16..+15.
#define P1_LOADA(BUF, TL) {                                                   \
    int g_ = (TL) >> 11, bp_ = (TL) & 2047;                                   \
    const float* ab_ = ctx + (size_t)(((g_*4096 + bp_*2)*32) + w*16 + arow)*256 + acol; \
    _Pragma("unroll")                                                         \
    for (int kk=0;kk<8;kk++){                                                 \
        BUF[2*kk]   = *(const v4f*)(ab_ + kk*32);                             \
        BUF[2*kk+1] = *(const v4f*)(ab_ + kk*32 + 4);                         \
    } }

#define P1_PROCESS(CUR, NXT, IT) {                                            \
    int tl_ = tile0 + (IT);                                                   \
    int pre_ = tile0 + (((IT)+1 < 12) ? (IT)+1 : 11);                         \
    P1_LOADA(NXT, pre_);   /* prefetch: in flight across MFMA+epilogue */     \
    v4f acc[9];                                                               \
    _Pragma("unroll")                                                         \
    for (int i=0;i<9;i++) acc[i] = (v4f){0.f,0.f,0.f,0.f};                    \
    _Pragma("unroll")                                                         \
    for (int kk=0;kk<8;kk++){                                                 \
        v8s afr = pack_bf8(CUR[2*kk], CUR[2*kk+1]);                           \
        _Pragma("unroll")                                                     \
        for (int cc=0;cc<9;cc++){                                             \
            v8s bfr = *(const v8s*)(bbase + (kk*9+cc)*512);                   \
            acc[cc] = __builtin_amdgcn_mfma_f32_16x16x32_bf16(afr, bfr, acc[cc], 0,0,0); \
        }                                                                     \
    }                                                                         \
    __syncthreads();   /* previous tile's z-phase done reading outT */        \
    {   int qr = (lane>>4)*4;                                                 \
        _Pragma("unroll")                                                     \
        for (int cc=0;cc<9;cc++){                                             \
            int col = cc*16 + (lane&15);                                      \
            _Pragma("unroll")                                                 \
            for (int r=0;r<4;r++)                                             \
                outT[(w*16 + qr + r)*148 + col] = acc[cc][r];                 \
        }                                                                     \
    }                                                                         \
    __syncthreads();                                                          \
    int g_ = tl_ >> 11, b0_ = (tl_ & 2047)*2;                                 \
    {   int p = t >> 4, i = t & 15;                                           \
        int b = p >> 3, h = p & 7;                                            \
        float nsv = ns[(b0_ + b)*8 + h];                                      \
        float s0 = outT[(b*32+i)*148 + 128 + h] + nsv;                        \
        float s1 = outT[(b*32+i+16)*148 + 128 + h] + nsv;                     \
        s0 = s0 > 0.f ? s0 : 0.2f*s0;                                         \
        s1 = s1 > 0.f ? s1 : 0.2f*s1;                                         \
        float mx = fmaxf(s0, s1);                                             \
        _Pragma("unroll")                                                     \
        for (int d=1; d<16; d<<=1) mx = fmaxf(mx, __shfl_xor(mx, d));         \
        float e0 = __expf(s0 - mx), e1 = __expf(s1 - mx);                     \
        float ssum = e0 + e1;                                                 \
        _Pragma("unroll")                                                     \
        for (int d=1; d<16; d<<=1) ssum += __shfl_xor(ssum, d);               \
        float inv = 1.0f / ssum;                                              \
        cf[(b*32 + i)*8 + h]      = e0 * inv;                                 \
        cf[(b*32 + i + 16)*8 + h] = e1 * inv;                                 \
    }                                                                         \
    __syncthreads();                                                          \
    {   int b = t >> 7, c = t & 127;                                          \
        float az[8];                                                          \
        _Pragma("unroll")                                                     \
        for (int h=0;h<8;h++) az[h]=0.f;                                      \
        for (int n=0;n<32;n++){                                               \
            float v = outT[(b*32+n)*148 + c];                                 \
            v4f c0 = *(const v4f*)&cf[(b*32+n)*8];                            \
            v4f c1 = *(const v4f*)&cf[(b*32+n)*8 + 4];                        \
            az[0] = fmaf(c0[0], v, az[0]); az[1] = fmaf(c0[1], v, az[1]);     \
            az[2] = fmaf(c0[2], v, az[2]); az[3] = fmaf(c0[3], v, az[3]);     \
            az[4] = fmaf(c1[0], v, az[4]); az[5] = fmaf(c1[1], v, az[5]);     \
            az[6] = fmaf(c1[2], v, az[6]); az[7] = fmaf(c1[3], v, az[7]);     \
        }                                                                     \
        size_t zb = ((size_t)(b0_ + b)*3 + g_)*1024;                          \
        _Pragma("unroll")                                                     \
        for (int h=0;h<8;h++) zb16[zb + h*128 + c] = f2bf(az[h] + bias[h*128 + c]); \
    } }

__global__ __launch_bounds__(256,2) void phase1(const float* __restrict__ ctx,
        const unsigned short* __restrict__ packB, const float* __restrict__ ns,
        const float* __restrict__ bias, unsigned short* __restrict__ zb16){
    __shared__ __align__(16) float outT[64*148];   // 37.9 KB (neigh f32 | scores f32)
    __shared__ float cf[2*32*8];                   // coef, 2 KB

    int t = threadIdx.x;
    int w = t >> 6, lane = t & 63;
    int arow = lane & 15, acol = (lane>>4)*8;
    const unsigned short* bbase = packB + lane*8;
    int tile0 = blockIdx.x * 12;                   // 512 blocks

    v4f A0[16], A1[16];
    P1_LOADA(A0, tile0);

    #pragma unroll 1
    for (int it=0; it<12; it+=2){
        P1_PROCESS(A0, A1, it);
        P1_PROCESS(A1, A0, it+1);
    }
}

// ---------------- phase 2: sem scores, LDS-free, A direct from bf16 zf ----------------
__global__ __launch_bounds__(256) void semk2(const unsigned short* __restrict__ zb16,
        const unsigned short* __restrict__ pack2, const float* __restrict__ sa,
        float* __restrict__ sws){
    __shared__ float red[16*4];
    int t = threadIdx.x, w = t>>6, lane = t&63;
    int r0 = blockIdx.x * 16;   // 768 blocks, 16 rows each
    v4f acc0 = (v4f){0.f,0.f,0.f,0.f};
    v4f acc1 = (v4f){0.f,0.f,0.f,0.f};
    const unsigned short* abase = zb16 + (size_t)(r0 + (lane&15))*1024 + (lane>>4)*8;
    #pragma unroll 4
    for (int kk=0; kk<32; kk++){
        v8s afr = *(const v8s*)(abase + kk*32);
        v8s b0  = *(const v8s*)(pack2 + (((kk*8 + w  )*64 + lane) << 3));
        v8s b1  = *(const v8s*)(pack2 + (((kk*8 + w+4)*64 + lane) << 3));
        acc0 = __builtin_amdgcn_mfma_f32_16x16x32_bf16(afr, b0, acc0, 0,0,0);
        acc1 = __builtin_amdgcn_mfma_f32_16x16x32_bf16(afr, b1, acc1, 0,0,0);
    }
    float sa0 = sa[w*16 + (lane&15)];
    float sa1 = sa[(w+4)*16 + (lane&15)];
    #pragma unroll
    for (int r=0;r<4;r++){
        float v = fmaf(tanhf(acc0[r]), sa0, tanhf(acc1[r]) * sa1);
        #pragma unroll
        for (int d=1; d<16; d<<=1) v += __shfl_xor(v, d);
        if ((lane&15)==0) red[((lane>>4)*4 + r)*4 + w] = v;
    }
    __syncthreads();
    if (t < 16)
        sws[r0 + t] = red[t*4] + red[t*4+1] + red[t*4+2] + red[t*4+3];
}

// ---------------- phase 3: softmax over G, pool, dense ----------------
__global__ __launch_bounds__(64) void final3(const unsigned short* __restrict__ zb16,
        const float* __restrict__ sws, const float* __restrict__ dw,
        const float* __restrict__ db, float* __restrict__ outp){
    int b = blockIdx.x;        // 4096
    int lane = threadIdx.x;    // 64
    float s0 = sws[b*3], s1 = sws[b*3+1], s2 = sws[b*3+2];
    float m = fmaxf(s0, fmaxf(s1, s2));
    float e0 = __expf(s0-m), e1 = __expf(s1-m), e2 = __expf(s2-m);
    float inv = 1.0f/(e0+e1+e2);
    float a0 = e0*inv, a1 = e1*inv, a2 = e2*inv;

    const unsigned short* z0 = zb16 + (size_t)b*3072 + lane*16;
    v8s za0 = *(const v8s*)(z0);          v8s za1 = *(const v8s*)(z0+8);
    v8s zb0 = *(const v8s*)(z0+1024);     v8s zb1 = *(const v8s*)(z0+1032);
    v8s zc0 = *(const v8s*)(z0+2048);     v8s zc1 = *(const v8s*)(z0+2056);
    float p[16];
    #pragma unroll
    for (int k=0;k<8;k++){
        p[k]   = a0*bf2f((unsigned short)za0[k]) + a1*bf2f((unsigned short)zb0[k]) + a2*bf2f((unsigned short)zc0[k]);
        p[k+8] = a0*bf2f((unsigned short)za1[k]) + a1*bf2f((unsigned short)zb1[k]) + a2*bf2f((unsigned short)zc1[k]);
    }
    float acc[16];
    #pragma unroll
    for (int l=0;l<16;l++) acc[l]=0.f;
    #pragma unroll
    for (int k=0;k<16;k++){
        const float* dr = dw + (lane*16 + k)*16;
        v4f d0 = *(const v4f*)(dr);
        v4f d1 = *(const v4f*)(dr+4);
        v4f d2 = *(const v4f*)(dr+8);
        v4f d3 = *(const v4f*)(dr+12);
        float pk = p[k];
        acc[0]=fmaf(pk,d0[0],acc[0]);  acc[1]=fmaf(pk,d0[1],acc[1]);
        acc[2]=fmaf(pk,d0[2],acc[2]);  acc[3]=fmaf(pk,d0[3],acc[3]);
        acc[4]=fmaf(pk,d1[0],acc[4]);  acc[5]=fmaf(pk,d1[1],acc[5]);
        acc[6]=fmaf(pk,d1[2],acc[6]);  acc[7]=fmaf(pk,d1[3],acc[7]);
        acc[8]=fmaf(pk,d2[0],acc[8]);  acc[9]=fmaf(pk,d2[1],acc[9]);
        acc[10]=fmaf(pk,d2[2],acc[10]); acc[11]=fmaf(pk,d2[3],acc[11]);
        acc[12]=fmaf(pk,d3[0],acc[12]); acc[13]=fmaf(pk,d3[1],acc[13]);
        acc[14]=fmaf(pk,d3[2],acc[14]); acc[15]=fmaf(pk,d3[3],acc[15]);
    }
    #pragma unroll
    for (int l=0;l<16;l++){
        float v = acc[l];
        #pragma unroll
        for (int d=1; d<64; d<<=1) v += __shfl_xor(v, d);
        acc[l] = v;
    }
    float myv = 0.f;
    #pragma unroll
    for (int l=0;l<16;l++) myv = (lane==l) ? acc[l] : myv;
    if (lane < 16) outp[b*16 + lane] = myv + db[lane];
}

extern "C" void kernel_launch(void* const* d_in, const int* in_sizes, int n_in,
                              void* d_out, int out_size, void* d_ws, size_t ws_size,
                              hipStream_t stream) {
    const float* targets  = (const float*)d_in[0];
    const float* contexts = (const float*)d_in[1];
    const float* kern     = (const float*)d_in[2];
    const float* ak       = (const float*)d_in[3];
    const float* bias     = (const float*)d_in[4];
    const float* semk     = (const float*)d_in[5];
    const float* sa       = (const float*)d_in[6];
    const float* dw       = (const float*)d_in[7];
    const float* db       = (const float*)d_in[8];
    float* outp = (float*)d_out;

    char* ws = (char*)d_ws;
    unsigned short* packB = (unsigned short*)(ws);             // 73728 B
    float* nsb            = (float*)(ws + 73728);              // 131072 B
    unsigned short* pack2 = (unsigned short*)(ws + 204800);    // 262144 B
    unsigned short* zb16  = (unsigned short*)(ws + 466944);    // 25165824 B
    float* sws            = (float*)(ws + 25632768);           // 49152 B

    prep_all<<<50, 256, 0, stream>>>(targets, kern, ak, semk, nsb, packB, pack2);
    phase1<<<512, 256, 0, stream>>>(contexts, packB, nsb, bias, zb16);
    semk2<<<768, 256, 0, stream>>>(zb16, pack2, sa, sws);
    final3<<<4096, 64, 0, stream>>>(zb16, sws, dw, db, outp);
}

// Round 5
// 197.551 us; speedup vs baseline: 2.0360x; 2.0360x over previous
//
#include <hip/hip_runtime.h>
#include <hip/hip_bf16.h>

typedef float v4f __attribute__((ext_vector_type(4)));
typedef short v8s __attribute__((ext_vector_type(8)));

__device__ __forceinline__ unsigned short f2bf(float x){
    unsigned u = __float_as_uint(x);
    u += 0x7FFFu + ((u >> 16) & 1u);
    return (unsigned short)(u >> 16);
}
__device__ __forceinline__ float bf2f(unsigned short h){
    return __uint_as_float(((unsigned)h) << 16);
}
__device__ __forceinline__ v8s pack_bf8(v4f a, v4f b){
    union { v8s s; __hip_bfloat162 h[4]; } u;
    u.h[0] = __float22bfloat162_rn(float2{a[0],a[1]});
    u.h[1] = __float22bfloat162_rn(float2{a[2],a[3]});
    u.h[2] = __float22bfloat162_rn(float2{b[0],b[1]});
    u.h[3] = __float22bfloat162_rn(float2{b[2],b[3]});
    return u.s;
}

// ---------------- merged prep kernel ----------------
__global__ __launch_bounds__(256) void prep_all(const float* __restrict__ targ,
        const float* __restrict__ kern, const float* __restrict__ ak,
        const float* __restrict__ semk, float* __restrict__ ns,
        unsigned short* __restrict__ packB, unsigned short* __restrict__ pack2){
    __shared__ float wsh[256*8];
    int blk = blockIdx.x, t = threadIdx.x;
    if (blk < 16){
        {   // W_node[d][h], d = t
            float a[8];
            #pragma unroll
            for (int h=0;h<8;h++) a[h]=0.f;
            const float* kr = kern + t*128;
            for (int c=0;c<128;c++){
                float kv = kr[c];
                #pragma unroll
                for (int h=0;h<8;h++) a[h] = fmaf(kv, ak[h*256+c], a[h]);
            }
            #pragma unroll
            for (int h=0;h<8;h++) wsh[t*8+h]=a[h];
        }
        __syncthreads();
        int b = blk*256 + t;
        float acc[8];
        #pragma unroll
        for (int h=0;h<8;h++) acc[h]=0.f;
        const float* tr = targ + (size_t)b*256;
        for (int d=0;d<256;d++){
            float tv = tr[d];
            #pragma unroll
            for (int h=0;h<8;h++) acc[h] = fmaf(tv, wsh[d*8+h], acc[h]);
        }
        #pragma unroll
        for (int h=0;h<8;h++) ns[b*8+h]=acc[h];
    } else if (blk < 18){
        {   // W_neigh[d][h], d = t
            float a[8];
            #pragma unroll
            for (int h=0;h<8;h++) a[h]=0.f;
            const float* kr = kern + t*128;
            for (int c=0;c<128;c++){
                float kv = kr[c];
                #pragma unroll
                for (int h=0;h<8;h++) a[h] = fmaf(kv, ak[h*256+128+c], a[h]);
            }
            #pragma unroll
            for (int h=0;h<8;h++) wsh[t*8+h]=a[h];
        }
        __syncthreads();
        int gt = (blk-16)*256 + t;            // 0..511
        for (int r=0;r<72;r++){
            int e = gt + r*512;                // < 36864
            int j = e & 7; int l = (e>>3) & 63;
            int fc = e >> 9; int cc = fc % 9; int kk = fc / 9;
            int d = kk*32 + (l>>4)*8 + j;
            int c = cc*16 + (l&15);
            float v;
            if (cc < 8) v = kern[d*128 + c];
            else { int h = c - 128; v = (h < 8) ? wsh[d*8+h] : 0.0f; }
            packB[e] = f2bf(v);
        }
    } else {
        int gt = (blk-18)*256 + t;            // 0..8191
        for (int r=0;r<16;r++){
            int e = gt + r*8192;               // < 131072
            int j = e & 7; int l = (e>>3) & 63;
            int cc = (e>>9) & 7; int gkk = e >> 12;   // 0..31
            int k = gkk*32 + (l>>4)*8 + j;
            int a2 = cc*16 + (l&15);
            pack2[e] = f2bf(semk[k*128 + a2]);
        }
    }
}

// ---------------- phase 1: barrier-free, wave-independent tiles ----------------
// 3072 blocks x 4 waves. Each WAVE owns one (g,b) = 32 rows x 144 cols.
// Scores softmaxed from accumulators (no LDS round-trip); neigh -> per-wave
// XOR-swizzled bf16 LDS; coef -> per-wave cf. NO __syncthreads anywhere.
__global__ __launch_bounds__(256,2) void phase1(const float* __restrict__ ctx,
        const unsigned short* __restrict__ packB, const float* __restrict__ ns,
        const float* __restrict__ bias, unsigned short* __restrict__ zb16){
    __shared__ __align__(16) unsigned short outT[4][32*128];  // 8 KB per wave
    __shared__ float cf[4][32*8];                             // 1 KB per wave

    int t = threadIdx.x, w = t >> 6, lane = t & 63;
    int wt = blockIdx.x*4 + w;            // 12288 = 3*4096
    int g = wt >> 12, b = wt & 4095;
    int q = lane >> 4, h = lane & 15;

    const float* ab = ctx + ((size_t)((g*4096 + b)*32) + h)*256 + q*8;
    const unsigned short* bbase = packB + lane*8;

    v4f acc0[9], acc1[9];
    #pragma unroll
    for (int i=0;i<9;i++){ acc0[i] = (v4f){0.f,0.f,0.f,0.f}; acc1[i] = (v4f){0.f,0.f,0.f,0.f}; }

    #pragma unroll
    for (int kk=0;kk<8;kk++){
        v8s a0 = pack_bf8(*(const v4f*)(ab + kk*32),        *(const v4f*)(ab + kk*32 + 4));
        v8s a1 = pack_bf8(*(const v4f*)(ab + 4096 + kk*32), *(const v4f*)(ab + 4096 + kk*32 + 4));
        #pragma unroll
        for (int cc=0;cc<9;cc++){
            v8s bf = *(const v8s*)(bbase + (kk*9+cc)*512);
            acc0[cc] = __builtin_amdgcn_mfma_f32_16x16x32_bf16(a0, bf, acc0[cc], 0,0,0);
            acc1[cc] = __builtin_amdgcn_mfma_f32_16x16x32_bf16(a1, bf, acc1[cc], 0,0,0);
        }
    }

    // ---- wave-local softmax from score accumulators (cc==8, col h<8) ----
    // lane holds rows q*4+r (m0) and 16+q*4+r (m1) of column h.
    {
        float nsv = (h < 8) ? ns[b*8 + h] : 0.f;
        float sc[8];
        #pragma unroll
        for (int r=0;r<4;r++){ sc[r] = acc0[8][r] + nsv; sc[4+r] = acc1[8][r] + nsv; }
        #pragma unroll
        for (int i=0;i<8;i++) sc[i] = sc[i] > 0.f ? sc[i] : 0.2f*sc[i];
        float mx = sc[0];
        #pragma unroll
        for (int i=1;i<8;i++) mx = fmaxf(mx, sc[i]);
        mx = fmaxf(mx, __shfl_xor(mx, 16));
        mx = fmaxf(mx, __shfl_xor(mx, 32));
        float e[8], sum = 0.f;
        #pragma unroll
        for (int i=0;i<8;i++){ e[i] = __expf(sc[i]-mx); sum += e[i]; }
        sum += __shfl_xor(sum, 16);
        sum += __shfl_xor(sum, 32);
        float inv = 1.0f / sum;
        if (h < 8){
            #pragma unroll
            for (int r=0;r<4;r++){
                cf[w][(q*4+r)*8 + h]      = e[r]*inv;
                cf[w][(16+q*4+r)*8 + h]   = e[4+r]*inv;
            }
        }
    }

    // ---- neigh (cc 0..7) -> per-wave LDS, bf16, XOR-swizzled rows ----
    #pragma unroll
    for (int cc=0;cc<8;cc++){
        #pragma unroll
        for (int r=0;r<4;r++){
            int row0 = q*4+r, row1 = 16+q*4+r;
            int byte0 = (row0*256 + (cc*16+h)*2) ^ ((row0&7)<<5);
            int byte1 = (row1*256 + (cc*16+h)*2) ^ ((row1&7)<<5);
            *(unsigned short*)((char*)outT[w] + byte0) = f2bf(acc0[cc][r]);
            *(unsigned short*)((char*)outT[w] + byte1) = f2bf(acc1[cc][r]);
        }
    }

    // ---- z[h][c] = sum_n coef[n][h] * neigh[n][c]; lane owns cols 2*lane, 2*lane+1 ----
    {
        float az0[8], az1[8];
        #pragma unroll
        for (int i=0;i<8;i++){ az0[i]=0.f; az1[i]=0.f; }
        for (int n=0;n<32;n++){
            int byte = (n*256 + lane*4) ^ ((n&7)<<5);
            unsigned v = *(const unsigned*)((const char*)outT[w] + byte);
            float v0 = bf2f((unsigned short)(v & 0xffffu));
            float v1 = bf2f((unsigned short)(v >> 16));
            v4f c0 = *(const v4f*)&cf[w][n*8];
            v4f c1 = *(const v4f*)&cf[w][n*8 + 4];
            az0[0]=fmaf(c0[0],v0,az0[0]); az0[1]=fmaf(c0[1],v0,az0[1]);
            az0[2]=fmaf(c0[2],v0,az0[2]); az0[3]=fmaf(c0[3],v0,az0[3]);
            az0[4]=fmaf(c1[0],v0,az0[4]); az0[5]=fmaf(c1[1],v0,az0[5]);
            az0[6]=fmaf(c1[2],v0,az0[6]); az0[7]=fmaf(c1[3],v0,az0[7]);
            az1[0]=fmaf(c0[0],v1,az1[0]); az1[1]=fmaf(c0[1],v1,az1[1]);
            az1[2]=fmaf(c0[2],v1,az1[2]); az1[3]=fmaf(c0[3],v1,az1[3]);
            az1[4]=fmaf(c1[0],v1,az1[4]); az1[5]=fmaf(c1[1],v1,az1[5]);
            az1[6]=fmaf(c1[2],v1,az1[6]); az1[7]=fmaf(c1[3],v1,az1[7]);
        }
        size_t zb = ((size_t)b*3 + g)*1024;
        int c0i = 2*lane;
        #pragma unroll
        for (int hh=0;hh<8;hh++){
            unsigned short p0 = f2bf(az0[hh] + bias[hh*128 + c0i]);
            unsigned short p1 = f2bf(az1[hh] + bias[hh*128 + c0i + 1]);
            unsigned pk = ((unsigned)p1 << 16) | (unsigned)p0;
            *(unsigned*)(zb16 + zb + hh*128 + c0i) = pk;
        }
    }
}

// ---------------- phase 2: sem scores, LDS-free, A direct from bf16 zf ----------------
__global__ __launch_bounds__(256) void semk2(const unsigned short* __restrict__ zb16,
        const unsigned short* __restrict__ pack2, const float* __restrict__ sa,
        float* __restrict__ sws){
    __shared__ float red[16*4];
    int t = threadIdx.x, w = t>>6, lane = t&63;
    int r0 = blockIdx.x * 16;   // 768 blocks, 16 rows each
    v4f acc0 = (v4f){0.f,0.f,0.f,0.f};
    v4f acc1 = (v4f){0.f,0.f,0.f,0.f};
    const unsigned short* abase = zb16 + (size_t)(r0 + (lane&15))*1024 + (lane>>4)*8;
    #pragma unroll 4
    for (int kk=0; kk<32; kk++){
        v8s afr = *(const v8s*)(abase + kk*32);
        v8s b0  = *(const v8s*)(pack2 + (((kk*8 + w  )*64 + lane) << 3));
        v8s b1  = *(const v8s*)(pack2 + (((kk*8 + w+4)*64 + lane) << 3));
        acc0 = __builtin_amdgcn_mfma_f32_16x16x32_bf16(afr, b0, acc0, 0,0,0);
        acc1 = __builtin_amdgcn_mfma_f32_16x16x32_bf16(afr, b1, acc1, 0,0,0);
    }
    float sa0 = sa[w*16 + (lane&15)];
    float sa1 = sa[(w+4)*16 + (lane&15)];
    #pragma unroll
    for (int r=0;r<4;r++){
        float v = fmaf(tanhf(acc0[r]), sa0, tanhf(acc1[r]) * sa1);
        #pragma unroll
        for (int d=1; d<16; d<<=1) v += __shfl_xor(v, d);
        if ((lane&15)==0) red[((lane>>4)*4 + r)*4 + w] = v;
    }
    __syncthreads();
    if (t < 16)
        sws[r0 + t] = red[t*4] + red[t*4+1] + red[t*4+2] + red[t*4+3];
}

// ---------------- phase 3: softmax over G, pool, dense ----------------
__global__ __launch_bounds__(64) void final3(const unsigned short* __restrict__ zb16,
        const float* __restrict__ sws, const float* __restrict__ dw,
        const float* __restrict__ db, float* __restrict__ outp){
    int b = blockIdx.x;        // 4096
    int lane = threadIdx.x;    // 64
    float s0 = sws[b*3], s1 = sws[b*3+1], s2 = sws[b*3+2];
    float m = fmaxf(s0, fmaxf(s1, s2));
    float e0 = __expf(s0-m), e1 = __expf(s1-m), e2 = __expf(s2-m);
    float inv = 1.0f/(e0+e1+e2);
    float a0 = e0*inv, a1 = e1*inv, a2 = e2*inv;

    const unsigned short* z0 = zb16 + (size_t)b*3072 + lane*16;
    v8s za0 = *(const v8s*)(z0);          v8s za1 = *(const v8s*)(z0+8);
    v8s zb0 = *(const v8s*)(z0+1024);     v8s zb1 = *(const v8s*)(z0+1032);
    v8s zc0 = *(const v8s*)(z0+2048);     v8s zc1 = *(const v8s*)(z0+2056);
    float p[16];
    #pragma unroll
    for (int k=0;k<8;k++){
        p[k]   = a0*bf2f((unsigned short)za0[k]) + a1*bf2f((unsigned short)zb0[k]) + a2*bf2f((unsigned short)zc0[k]);
        p[k+8] = a0*bf2f((unsigned short)za1[k]) + a1*bf2f((unsigned short)zb1[k]) + a2*bf2f((unsigned short)zc1[k]);
    }
    float acc[16];
    #pragma unroll
    for (int l=0;l<16;l++) acc[l]=0.f;
    #pragma unroll
    for (int k=0;k<16;k++){
        const float* dr = dw + (lane*16 + k)*16;
        v4f d0 = *(const v4f*)(dr);
        v4f d1 = *(const v4f*)(dr+4);
        v4f d2 = *(const v4f*)(dr+8);
        v4f d3 = *(const v4f*)(dr+12);
        float pk = p[k];
        acc[0]=fmaf(pk,d0[0],acc[0]);  acc[1]=fmaf(pk,d0[1],acc[1]);
        acc[2]=fmaf(pk,d0[2],acc[2]);  acc[3]=fmaf(pk,d0[3],acc[3]);
        acc[4]=fmaf(pk,d1[0],acc[4]);  acc[5]=fmaf(pk,d1[1],acc[5]);
        acc[6]=fmaf(pk,d1[2],acc[6]);  acc[7]=fmaf(pk,d1[3],acc[7]);
        acc[8]=fmaf(pk,d2[0],acc[8]);  acc[9]=fmaf(pk,d2[1],acc[9]);
        acc[10]=fmaf(pk,d2[2],acc[10]); acc[11]=fmaf(pk,d2[3],acc[11]);
        acc[12]=fmaf(pk,d3[0],acc[12]); acc[13]=fmaf(pk,d3[1],acc[13]);
        acc[14]=fmaf(pk,d3[2],acc[14]); acc[15]=fmaf(pk,d3[3],acc[15]);
    }
    #pragma unroll
    for (int l=0;l<16;l++){
        float v = acc[l];
        #pragma unroll
        for (int d=1; d<64; d<<=1) v += __shfl_xor(v, d);
        acc[l] = v;
    }
    float myv = 0.f;
    #pragma unroll
    for (int l=0;l<16;l++) myv = (lane==l) ? acc[l] : myv;
    if (lane < 16) outp[b*16 + lane] = myv + db[lane];
}

extern "C" void kernel_launch(void* const* d_in, const int* in_sizes, int n_in,
                              void* d_out, int out_size, void* d_ws, size_t ws_size,
                              hipStream_t stream) {
    const float* targets  = (const float*)d_in[0];
    const float* contexts = (const float*)d_in[1];
    const float* kern     = (const float*)d_in[2];
    const float* ak       = (const float*)d_in[3];
    const float* bias     = (const float*)d_in[4];
    const float* semk     = (const float*)d_in[5];
    const float* sa       = (const float*)d_in[6];
    const float* dw       = (const float*)d_in[7];
    const float* db       = (const float*)d_in[8];
    float* outp = (float*)d_out;

    char* ws = (char*)d_ws;
    unsigned short* packB = (unsigned short*)(ws);             // 73728 B
    float* nsb            = (float*)(ws + 73728);              // 131072 B
    unsigned short* pack2 = (unsigned short*)(ws + 204800);    // 262144 B
    unsigned short* zb16  = (unsigned short*)(ws + 466944);    // 25165824 B
    float* sws            = (float*)(ws + 25632768);           // 49152 B

    prep_all<<<50, 256, 0, stream>>>(targets, kern, ak, semk, nsb, packB, pack2);
    phase1<<<3072, 256, 0, stream>>>(contexts, packB, nsb, bias, zb16);
    semk2<<<768, 256, 0, stream>>>(zb16, pack2, sa, sws);
    final3<<<4096, 64, 0, stream>>>(zb16, sws, dw, db, outp);
}